// Round 11
// baseline (279.552 us; speedup 1.0000x reference)
//
#include <hip/hip_runtime.h>

#define GROUPS 32
#define EPS 1e-5f

typedef unsigned short u16;
typedef __bf16 bf16x8 __attribute__((ext_vector_type(8)));
typedef float f32x4 __attribute__((ext_vector_type(4)));

__device__ __forceinline__ u16 f2bf(float f) {
  unsigned x = __builtin_bit_cast(unsigned, f);
  x += 0x7FFFu + ((x >> 16) & 1u);
  return (u16)(x >> 16);
}
__device__ __forceinline__ float bf2f(u16 u) {
  unsigned x = ((unsigned)u) << 16;
  return __builtin_bit_cast(float, x);
}

__device__ __forceinline__ void gload_lds16(const void* g, void* l) {
  __builtin_amdgcn_global_load_lds(
      (const __attribute__((address_space(1))) void*)g,
      (__attribute__((address_space(3))) void*)l, 16, 0, 0);
}

// ---------------- weight fp32 -> bf16 (all 4 weights, one dispatch) --------
__global__ __launch_bounds__(256) void cvt_kernel(
    const float* __restrict__ wq, const float* __restrict__ wk,
    const float* __restrict__ wv, const float* __restrict__ wo,
    u16* __restrict__ Wqk, u16* __restrict__ Wv, u16* __restrict__ Wo,
    int n) {
  int i = (blockIdx.x * 256 + threadIdx.x) * 4;
  if (i >= n) return;
  const float* src;
  u16* dst;
  switch (blockIdx.y) {
    case 0: src = wq; dst = Wqk; break;
    case 1: src = wk; dst = Wqk + n; break;
    case 2: src = wv; dst = Wv; break;
    default: src = wo; dst = Wo; break;
  }
  float4 v = *(const float4*)&src[i];
  ushort4 o;
  o.x = f2bf(v.x); o.y = f2bf(v.y); o.z = f2bf(v.z); o.w = f2bf(v.w);
  *(ushort4*)&dst[i] = o;
}

// ---------------- bias concat bq||bk -> fp32[1024] ----------------
__global__ __launch_bounds__(256) void biascat_kernel(
    const float* __restrict__ bq, const float* __restrict__ bk,
    float* __restrict__ bqk, int C) {
  int i = blockIdx.x * 256 + threadIdx.x;
  if (i < C) bqk[i] = bq[i];
  else if (i < 2 * C) bqk[i] = bk[i - C];
}

// ---------------- GroupNorm -> HT [N, S, C] bf16 ----------------
__global__ __launch_bounds__(256) void groupnorm_kernel(
    const float* __restrict__ x, const float* __restrict__ gamma,
    const float* __restrict__ beta, u16* __restrict__ HT, int C, int S) {
  const int cpg = C / GROUPS;  // 16
  __shared__ float xs[16 * 1024];  // 64 KB, layout == global slab [c][sp]
  __shared__ float rs[4], rss[4];
  int n = blockIdx.x / GROUPS;
  int g = blockIdx.x % GROUPS;
  const float* xb = x + ((size_t)n * C + (size_t)g * cpg) * S;
  int tid = threadIdx.x;
  int cnt = cpg * S;  // 16384
  float s = 0.f, ss = 0.f;
  for (int i = tid * 4; i < cnt; i += 256 * 4) {
    float4 v = *(const float4*)&xb[i];
    *(float4*)&xs[i] = v;
    s += v.x + v.y + v.z + v.w;
    ss += v.x * v.x + v.y * v.y + v.z * v.z + v.w * v.w;
  }
  for (int o = 32; o > 0; o >>= 1) {
    s += __shfl_xor(s, o);
    ss += __shfl_xor(ss, o);
  }
  int wave = tid >> 6, lane = tid & 63;
  if (lane == 0) { rs[wave] = s; rss[wave] = ss; }
  __syncthreads();
  float S1 = rs[0] + rs[1] + rs[2] + rs[3];
  float S2 = rss[0] + rss[1] + rss[2] + rss[3];
  float mean = S1 / (float)cnt;
  float var = S2 / (float)cnt - mean * mean;
  float rstd = rsqrtf(var + EPS);
  float gm[16], bt[16];
#pragma unroll
  for (int c = 0; c < 16; ++c) {
    float gmv = gamma[g * cpg + c] * rstd;
    gm[c] = gmv;
    bt[c] = beta[g * cpg + c] - mean * gmv;
  }
  for (int i = 0; i < S; i += 256) {
    int sp = i + tid;
    u16 outv[16];
#pragma unroll
    for (int c = 0; c < 16; ++c) {
      float h = xs[c * 1024 + sp] * gm[c] + bt[c];
      outv[c] = f2bf(h);
    }
    u16* dst = HT + ((size_t)n * S + sp) * C + g * cpg;
    *(int4*)dst = *(int4*)&outv[0];
    *(int4*)&dst[8] = *(int4*)&outv[8];
  }
}

// =================== 256x256x32 2-phase GEMM (8 waves) =====================
// Out[m][n] = scale*sum_k A[m][k]*B[n][k] (+bias/residual)
// Proven 2-phase schedule: per K-tile { STAGE(next buf) first; compute;
// vmcnt(0); s_barrier }. 64 KB LDS dbuf (BK=32) -> 2 blocks/CU resident.
// 256^2 tile halves staged panel bytes per output vs 256x128
// (staged prop 1/BM+1/BN).  Batch->XCD locality swizzle.
// LDS line layout (proven 0-conflict): two rows interleave into one 64-elem
// line; granule (l,p) holds global (row=2l+(q>>2), kslot=q&3), q=p^(l&7).
__global__ __launch_bounds__(512, 2) void gemm256_kernel(
    const u16* __restrict__ A, long lda, long strideA,
    const u16* __restrict__ B, long ldb, long strideB,
    void* __restrict__ Out, long ldo, long strideO, int out_fp32,
    const float* __restrict__ bias, int bias_mode,  // 0 none, 1 row, 2 col
    float scale, const float* __restrict__ residual, int K, int nbx, int nby) {
  __shared__ u16 lds[32768];  // 64 KiB
  u16* As0 = lds;             // 256x32 = 8192 u16 (1024 granules)
  u16* Bs0 = lds + 8192;
  u16* As1 = lds + 16384;
  u16* Bs1 = lds + 24576;

  int tid = threadIdx.x;
  int wave = tid >> 6, lane = tid & 63;
  int wr = wave >> 2, wc = wave & 3;   // 2 x 4 wave grid, 128x64 per wave
  int l15 = lane & 15, l4 = lane >> 4;

  int orig = blockIdx.x;
  int tilesPB = nbx * nby;
  int nz = gridDim.x / tilesPB;
  int z, rem;
  if ((nz & 7) == 0) {        // batch->XCD mapping (XCD e gets z = e, e+8, ..)
    int e = orig & 7, j = orig >> 3;
    z = e + 8 * (j / tilesPB);
    rem = j % tilesPB;
  } else {
    int swz = ((gridDim.x & 7) == 0)
                  ? (orig & 7) * (gridDim.x >> 3) + (orig >> 3) : orig;
    z = swz / tilesPB; rem = swz % tilesPB;
  }
  int bx = rem % nbx, by = rem / nbx;

  const u16* Ab = A + (long)z * strideA + (long)by * 256 * lda;
  const u16* Bb = B + (long)z * strideB + (long)bx * 256 * ldb;

  // stage one 256x32 A tile + 256x32 B tile (2048 granules, 4/thread)
  auto STAGE = [&](u16* Ad, u16* Bd, int kt) {
#pragma unroll
    for (int i = 0; i < 2; ++i) {
      int c = i * 512 + tid;            // 0..1023
      int l = c >> 3, p = c & 7;
      int q = p ^ (l & 7);
      int row = 2 * l + (q >> 2);
      long koff = (long)kt * 32 + (q & 3) * 8;
      int lbase = (i * 512 + wave * 64) * 8;
      gload_lds16(Ab + (long)row * lda + koff, Ad + lbase);
      gload_lds16(Bb + (long)row * ldb + koff, Bd + lbase);
    }
  };

  f32x4 acc[8][4] = {};

  auto COMPUTE = [&](const u16* Asrc, const u16* Bsrc) {
    bf16x8 af[8], bfr[4];
#pragma unroll
    for (int m = 0; m < 8; ++m) {
      int R = wr * 128 + m * 16 + l15;
      int line = R >> 1;
      int p = ((R & 1) * 4 + l4) ^ (line & 7);
      af[m] = *(const bf16x8*)&Asrc[line * 64 + p * 8];
    }
#pragma unroll
    for (int n = 0; n < 4; ++n) {
      int R = wc * 64 + n * 16 + l15;
      int line = R >> 1;
      int p = ((R & 1) * 4 + l4) ^ (line & 7);
      bfr[n] = *(const bf16x8*)&Bsrc[line * 64 + p * 8];
    }
#pragma unroll
    for (int m = 0; m < 8; ++m)
#pragma unroll
      for (int n = 0; n < 4; ++n)
        acc[m][n] = __builtin_amdgcn_mfma_f32_16x16x32_bf16(
            af[m], bfr[n], acc[m][n], 0, 0, 0);
  };

  int NT = K >> 5;
  u16 *Ar = As0, *Br = Bs0, *Aw = As1, *Bw = Bs1;

  STAGE(Ar, Br, 0);
  asm volatile("s_waitcnt vmcnt(0)" ::: "memory");
  __builtin_amdgcn_sched_barrier(0);
  __builtin_amdgcn_s_barrier();
  __builtin_amdgcn_sched_barrier(0);

  for (int t = 0; t < NT - 1; ++t) {
    STAGE(Aw, Bw, t + 1);       // issue next-tile loads first
    COMPUTE(Ar, Br);            // they fly under ds_read + MFMA
    asm volatile("s_waitcnt vmcnt(0)" ::: "memory");
    __builtin_amdgcn_sched_barrier(0);
    __builtin_amdgcn_s_barrier();
    __builtin_amdgcn_sched_barrier(0);
    u16* tp;
    tp = Ar; Ar = Aw; Aw = tp;
    tp = Br; Br = Bw; Bw = tp;
  }
  COMPUTE(Ar, Br);

  long orow0 = (long)by * 256 + wr * 128;
  long ocol0 = (long)bx * 256 + wc * 64;
#pragma unroll
  for (int m = 0; m < 8; ++m) {
#pragma unroll
    for (int n = 0; n < 4; ++n) {
#pragma unroll
      for (int r = 0; r < 4; ++r) {
        long row = orow0 + m * 16 + l4 * 4 + r;
        long col = ocol0 + n * 16 + l15;
        float v = acc[m][n][r] * scale;
        if (bias_mode == 1) v += bias[row];
        else if (bias_mode == 2) v += bias[col];
        long off = (long)z * strideO + row * ldo + col;
        if (residual) v += residual[off];
        if (out_fp32) ((float*)Out)[off] = v;
        else ((u16*)Out)[off] = f2bf(v);
      }
    }
  }
}

// ---------------- softmax over rows of P [rows, S] bf16, in place ----------
__global__ __launch_bounds__(256) void softmax_kernel(u16* __restrict__ P, int S) {
  size_t row = blockIdx.x;
  u16* p = P + row * (size_t)S;
  int tid = threadIdx.x;
  ushort4 u = *(const ushort4*)&p[tid * 4];
  float v0 = bf2f(u.x), v1 = bf2f(u.y), v2 = bf2f(u.z), v3 = bf2f(u.w);
  float m = fmaxf(fmaxf(v0, v1), fmaxf(v2, v3));
  for (int o = 32; o > 0; o >>= 1) m = fmaxf(m, __shfl_xor(m, o));
  __shared__ float redm[4], reds[4];
  int wave = tid >> 6, lane = tid & 63;
  if (lane == 0) redm[wave] = m;
  __syncthreads();
  m = fmaxf(fmaxf(redm[0], redm[1]), fmaxf(redm[2], redm[3]));
  float e0 = __expf(v0 - m), e1 = __expf(v1 - m);
  float e2 = __expf(v2 - m), e3 = __expf(v3 - m);
  float s = e0 + e1 + e2 + e3;
  for (int o = 32; o > 0; o >>= 1) s += __shfl_xor(s, o);
  if (lane == 0) reds[wave] = s;
  __syncthreads();
  s = reds[0] + reds[1] + reds[2] + reds[3];
  float inv = 1.f / s;
  ushort4 o4;
  o4.x = f2bf(e0 * inv); o4.y = f2bf(e1 * inv);
  o4.z = f2bf(e2 * inv); o4.w = f2bf(e3 * inv);
  *(ushort4*)&p[tid * 4] = o4;
}

extern "C" void kernel_launch(void* const* d_in, const int* in_sizes, int n_in,
                              void* d_out, int out_size, void* d_ws, size_t ws_size,
                              hipStream_t stream) {
  const float* x = (const float*)d_in[0];
  const float* gamma = (const float*)d_in[1];
  const float* beta = (const float*)d_in[2];
  const float* wq = (const float*)d_in[3];
  const float* bq = (const float*)d_in[4];
  const float* wk = (const float*)d_in[5];
  const float* bk = (const float*)d_in[6];
  const float* wv = (const float*)d_in[7];
  const float* bv = (const float*)d_in[8];
  const float* wo = (const float*)d_in[9];
  const float* bo = (const float*)d_in[10];

  const int C = 512, S = 1024;
  const int N = in_sizes[0] / (C * S);  // 16
  const long SC = (long)S * C;
  const long S2C = (long)S * 2 * C;
  const long SS = (long)S * S;
  const int CC = C * C;

  char* ws = (char*)d_ws;
  const size_t MB = 1024 * 1024;
  u16* HT = (u16*)(ws + 0 * MB);      // [N,S,C]   0..16 MB
  u16* QKT = (u16*)(ws + 16 * MB);    // [N,S,2C]  16..48 MB
  u16* Vb = (u16*)(ws + 48 * MB);     // [N,C,S]   48..64 MB
  u16* P = (u16*)(ws + 64 * MB);      // [N,S,S]   64..96 MB
  u16* Wqk = (u16*)(ws + 96 * MB);    // [2C,C]    96..97 MB
  u16* Wv = Wqk + 2 * CC;             // 97..97.5
  u16* Wo = Wv + CC;                  // 97.5..98
  float* bqk = (float*)(Wo + CC);     // [2C] 4 KB
  u16* H2T = HT;                      // overlay: HT dead after V-GEMM

  cvt_kernel<<<dim3(CC / 1024, 4), 256, 0, stream>>>(wq, wk, wv, wo, Wqk, Wv, Wo, CC);
  biascat_kernel<<<4, 256, 0, stream>>>(bq, bk, bqk, C);
  groupnorm_kernel<<<N * GROUPS, 256, 0, stream>>>(x, gamma, beta, HT, C, S);

  const float scl = 1.0f / sqrtf((float)C);

  // fused Q,K projection: QKT[s][j] = sum_c HT[s][c]*Wqk[j][c] + bqk[j]
  gemm256_kernel<<<dim3((S / 256) * (2 * C / 256) * N), 512, 0, stream>>>(
      HT, C, SC, Wqk, C, 0, QKT, 2 * C, S2C, 0, bqk, 2, 1.f, nullptr, C,
      2 * C / 256, S / 256);
  // V[c][s] = sum_k Wv[c][k]*HT[s][k] + bv[c]
  gemm256_kernel<<<dim3((C / 256) * (S / 256) * N), 512, 0, stream>>>(
      Wv, C, 0, HT, C, SC, Vb, S, SC, 0, bv, 1, 1.f, nullptr, C,
      S / 256, C / 256);
  // P[s][t] = scl * sum_c Q[s][c]*K[t][c]
  gemm256_kernel<<<dim3((S / 256) * (S / 256) * N), 512, 0, stream>>>(
      QKT, 2 * C, S2C, QKT + C, 2 * C, S2C, P, S, SS, 0, nullptr, 0, scl,
      nullptr, C, S / 256, S / 256);
  softmax_kernel<<<N * S, 256, 0, stream>>>(P, S);
  // H2T[s][c] = sum_t P[s][t]*V[c][t]
  gemm256_kernel<<<dim3((S / 256) * (C / 256) * N), 512, 0, stream>>>(
      P, S, SS, Vb, S, SC, H2T, C, SC, 0, nullptr, 0, 1.f, nullptr, S,
      C / 256, S / 256);
  // out[c][s] = x + bo[c] + sum_k Wo[c][k]*H2T[s][k]   (fp32)
  gemm256_kernel<<<dim3((C / 256) * (S / 256) * N), 512, 0, stream>>>(
      Wo, C, 0, H2T, C, SC, d_out, S, SC, 1, bo, 1, 1.f, x, C,
      S / 256, C / 256);
}

// Round 12
// 256.359 us; speedup vs baseline: 1.0905x; 1.0905x over previous
//
#include <hip/hip_runtime.h>

#define GROUPS 32
#define EPS 1e-5f

typedef unsigned short u16;
typedef __bf16 bf16x8 __attribute__((ext_vector_type(8)));
typedef float f32x4 __attribute__((ext_vector_type(4)));

__device__ __forceinline__ u16 f2bf(float f) {
  unsigned x = __builtin_bit_cast(unsigned, f);
  x += 0x7FFFu + ((x >> 16) & 1u);
  return (u16)(x >> 16);
}
__device__ __forceinline__ float bf2f(u16 u) {
  unsigned x = ((unsigned)u) << 16;
  return __builtin_bit_cast(float, x);
}

__device__ __forceinline__ void gload_lds16(const void* g, void* l) {
  __builtin_amdgcn_global_load_lds(
      (const __attribute__((address_space(1))) void*)g,
      (__attribute__((address_space(3))) void*)l, 16, 0, 0);
}

// ---------------- weight fp32 -> bf16 (all 4 weights, one dispatch) --------
__global__ __launch_bounds__(256) void cvt_kernel(
    const float* __restrict__ wq, const float* __restrict__ wk,
    const float* __restrict__ wv, const float* __restrict__ wo,
    u16* __restrict__ Wqk, u16* __restrict__ Wv, u16* __restrict__ Wo,
    int n) {
  int i = (blockIdx.x * 256 + threadIdx.x) * 4;
  if (i >= n) return;
  const float* src;
  u16* dst;
  switch (blockIdx.y) {
    case 0: src = wq; dst = Wqk; break;
    case 1: src = wk; dst = Wqk + n; break;
    case 2: src = wv; dst = Wv; break;
    default: src = wo; dst = Wo; break;
  }
  float4 v = *(const float4*)&src[i];
  ushort4 o;
  o.x = f2bf(v.x); o.y = f2bf(v.y); o.z = f2bf(v.z); o.w = f2bf(v.w);
  *(ushort4*)&dst[i] = o;
}

// ---------------- bias concat bq||bk -> fp32[1024] ----------------
__global__ __launch_bounds__(256) void biascat_kernel(
    const float* __restrict__ bq, const float* __restrict__ bk,
    float* __restrict__ bqk, int C) {
  int i = blockIdx.x * 256 + threadIdx.x;
  if (i < C) bqk[i] = bq[i];
  else if (i < 2 * C) bqk[i] = bk[i - C];
}

// ---------------- GroupNorm -> HT [N, S, C] bf16 ----------------
__global__ __launch_bounds__(256) void groupnorm_kernel(
    const float* __restrict__ x, const float* __restrict__ gamma,
    const float* __restrict__ beta, u16* __restrict__ HT, int C, int S) {
  const int cpg = C / GROUPS;  // 16
  __shared__ float xs[16 * 1024];
  __shared__ float rs[4], rss[4];
  int n = blockIdx.x / GROUPS;
  int g = blockIdx.x % GROUPS;
  const float* xb = x + ((size_t)n * C + (size_t)g * cpg) * S;
  int tid = threadIdx.x;
  int cnt = cpg * S;
  float s = 0.f, ss = 0.f;
  for (int i = tid * 4; i < cnt; i += 256 * 4) {
    float4 v = *(const float4*)&xb[i];
    *(float4*)&xs[i] = v;
    s += v.x + v.y + v.z + v.w;
    ss += v.x * v.x + v.y * v.y + v.z * v.z + v.w * v.w;
  }
  for (int o = 32; o > 0; o >>= 1) {
    s += __shfl_xor(s, o);
    ss += __shfl_xor(ss, o);
  }
  int wave = tid >> 6, lane = tid & 63;
  if (lane == 0) { rs[wave] = s; rss[wave] = ss; }
  __syncthreads();
  float S1 = rs[0] + rs[1] + rs[2] + rs[3];
  float S2 = rss[0] + rss[1] + rss[2] + rss[3];
  float mean = S1 / (float)cnt;
  float var = S2 / (float)cnt - mean * mean;
  float rstd = rsqrtf(var + EPS);
  float gm[16], bt[16];
#pragma unroll
  for (int c = 0; c < 16; ++c) {
    float gmv = gamma[g * cpg + c] * rstd;
    gm[c] = gmv;
    bt[c] = beta[g * cpg + c] - mean * gmv;
  }
  for (int i = 0; i < S; i += 256) {
    int sp = i + tid;
    u16 outv[16];
#pragma unroll
    for (int c = 0; c < 16; ++c) {
      float h = xs[c * 1024 + sp] * gm[c] + bt[c];
      outv[c] = f2bf(h);
    }
    u16* dst = HT + ((size_t)n * S + sp) * C + g * cpg;
    *(int4*)dst = *(int4*)&outv[0];
    *(int4*)&dst[8] = *(int4*)&outv[8];
  }
}

// =================== 256x128x32 2-phase GEMM (8 waves) =====================
// Round-8 best structure + batch->XCD locality z-map.
__global__ __launch_bounds__(512, 4) void gemm256x128_kernel(
    const u16* __restrict__ A, long lda, long strideA,
    const u16* __restrict__ B, long ldb, long strideB,
    void* __restrict__ Out, long ldo, long strideO, int out_fp32,
    const float* __restrict__ bias, int bias_mode,  // 0 none, 1 row, 2 col
    float scale, const float* __restrict__ residual, int K, int nbx, int nby) {
  __shared__ u16 lds[24576];  // 48 KiB
  u16* As0 = lds;
  u16* Bs0 = lds + 8192;
  u16* As1 = lds + 12288;
  u16* Bs1 = lds + 20480;

  int tid = threadIdx.x;
  int wave = tid >> 6, lane = tid & 63;
  int wr = wave >> 1, wc = wave & 1;
  int l15 = lane & 15, l4 = lane >> 4;

  int orig = blockIdx.x;
  int tilesPB = nbx * nby;
  int nz = gridDim.x / tilesPB;
  int z, rem;
  if ((nz & 7) == 0) {        // batch->XCD mapping
    int e = orig & 7, j = orig >> 3;
    z = e + 8 * (j / tilesPB);
    rem = j % tilesPB;
  } else {
    int swz = ((gridDim.x & 7) == 0)
                  ? (orig & 7) * (gridDim.x >> 3) + (orig >> 3) : orig;
    z = swz / tilesPB; rem = swz % tilesPB;
  }
  int bx = rem % nbx, by = rem / nbx;

  const u16* Ab = A + (long)z * strideA + (long)by * 256 * lda;
  const u16* Bb = B + (long)z * strideB + (long)bx * 128 * ldb;

  auto STAGE = [&](u16* Ad, u16* Bd, int kt) {
#pragma unroll
    for (int i = 0; i < 2; ++i) {       // A granules
      int c = i * 512 + tid;
      int l = c >> 3, p = c & 7;
      int q = p ^ (l & 7);
      int row = 2 * l + (q >> 2);
      long koff = (long)kt * 32 + (q & 3) * 8;
      int lbase = (i * 512 + wave * 64) * 8;
      gload_lds16(Ab + (long)row * lda + koff, Ad + lbase);
    }
    {                                   // B granules
      int c = tid;
      int l = c >> 3, p = c & 7;
      int q = p ^ (l & 7);
      int row = 2 * l + (q >> 2);
      long koff = (long)kt * 32 + (q & 3) * 8;
      int lbase = (wave * 64) * 8;
      gload_lds16(Bb + (long)row * ldb + koff, Bd + lbase);
    }
  };

  f32x4 acc[4][4] = {};

  auto COMPUTE = [&](const u16* Asrc, const u16* Bsrc) {
    bf16x8 af[4], bfr[4];
#pragma unroll
    for (int m = 0; m < 4; ++m) {
      int R = wr * 64 + m * 16 + l15;
      int line = R >> 1;
      int p = ((R & 1) * 4 + l4) ^ (line & 7);
      af[m] = *(const bf16x8*)&Asrc[line * 64 + p * 8];
    }
#pragma unroll
    for (int n = 0; n < 4; ++n) {
      int R = wc * 64 + n * 16 + l15;
      int line = R >> 1;
      int p = ((R & 1) * 4 + l4) ^ (line & 7);
      bfr[n] = *(const bf16x8*)&Bsrc[line * 64 + p * 8];
    }
#pragma unroll
    for (int m = 0; m < 4; ++m)
#pragma unroll
      for (int n = 0; n < 4; ++n)
        acc[m][n] = __builtin_amdgcn_mfma_f32_16x16x32_bf16(
            af[m], bfr[n], acc[m][n], 0, 0, 0);
  };

  int NT = K >> 5;
  u16 *Ar = As0, *Br = Bs0, *Aw = As1, *Bw = Bs1;

  STAGE(Ar, Br, 0);
  asm volatile("s_waitcnt vmcnt(0)" ::: "memory");
  __builtin_amdgcn_sched_barrier(0);
  __builtin_amdgcn_s_barrier();
  __builtin_amdgcn_sched_barrier(0);

  for (int t = 0; t < NT - 1; ++t) {
    STAGE(Aw, Bw, t + 1);
    COMPUTE(Ar, Br);
    asm volatile("s_waitcnt vmcnt(0)" ::: "memory");
    __builtin_amdgcn_sched_barrier(0);
    __builtin_amdgcn_s_barrier();
    __builtin_amdgcn_sched_barrier(0);
    u16* tp;
    tp = Ar; Ar = Aw; Aw = tp;
    tp = Br; Br = Bw; Bw = tp;
  }
  COMPUTE(Ar, Br);

  long orow0 = (long)by * 256 + wr * 64;
  long ocol0 = (long)bx * 128 + wc * 64;
#pragma unroll
  for (int m = 0; m < 4; ++m) {
#pragma unroll
    for (int n = 0; n < 4; ++n) {
#pragma unroll
      for (int r = 0; r < 4; ++r) {
        long row = orow0 + m * 16 + l4 * 4 + r;
        long col = ocol0 + n * 16 + l15;
        float v = acc[m][n][r] * scale;
        if (bias_mode == 1) v += bias[row];
        else if (bias_mode == 2) v += bias[col];
        long off = (long)z * strideO + row * ldo + col;
        if (residual) v += residual[off];
        if (out_fp32) ((float*)Out)[off] = v;
        else ((u16*)Out)[off] = f2bf(v);
      }
    }
  }
}

// ================= flash attention: QK^T + softmax + PV fused ==============
// Block: 32 Q-rows x full C=512 output, one batch. 8 waves.
// Per KV tile (32 cols): S[32][32] via split-K (wave halves write 2 partials,
// summed in the softmax LDS read); online softmax (m,l per row, 16-lane
// groups); P bf16 in LDS; O rescale; PV MFMA.
// K staged under PV (its buffer free after S-compute barrier), V staged
// under S-compute (free after prev PV barrier). Single-buffered.
// Swizzles: K granule g at phys g^(row&31); V granule g at phys
// g^((row&3)^((row>>2)&3)).
__global__ __launch_bounds__(512, 4) void flash_kernel(
    const u16* __restrict__ QKT, const u16* __restrict__ Vb,
    u16* __restrict__ H2T, float scl) {
  const int S = 1024, C = 512;
  __shared__ u16 Kl[32 * 512];      // 32 KB
  __shared__ u16 Vl[512 * 32];      // 32 KB
  __shared__ float Sl[2][32][33];   // 8.25 KB (split-K partials)
  __shared__ u16 Pl[32][40];        // 2.5 KB (40: 16B-aligned b128 rows)
  __shared__ float rowf[32];        // per-row broadcast (scale / 1/l)

  int tid = threadIdx.x;
  int w = tid >> 6, lane = tid & 63;
  int l15 = lane & 15, l4 = lane >> 4;
  int wm = w & 3, wh = w >> 2;      // frag id, k-half
  int sm = wm >> 1, sn = wm & 1;    // S-fragment coords

  int b = blockIdx.x;
  int e = b & 7, j = b >> 3;        // batch->XCD: batch z on XCD z&7
  int z = e + 8 * (j >> 5);
  int qb = j & 31;
  int q0 = qb * 32;

  const u16* Qg = QKT + (size_t)z * S * 2 * C;   // row stride 2C
  const u16* Kg = Qg + C;
  const u16* Vg = Vb + (size_t)z * C * S;        // row stride S
  u16* Og = H2T + (size_t)z * S * C;

  // Q fragment in registers: rows 16*sm + l15, c-half wh*256
  bf16x8 qreg[8];
  {
    const u16* qp = Qg + (size_t)(q0 + sm * 16 + l15) * 2 * C + wh * 256 + l4 * 8;
#pragma unroll
    for (int kk = 0; kk < 8; ++kk)
      qreg[kk] = *(const bf16x8*)(qp + kk * 32);
  }

  auto STAGE_K = [&](int t0) {       // K-tile: 32 t-rows x 512 c
#pragma unroll
    for (int i = 0; i < 4; ++i) {
      int c = i * 512 + tid;         // granule 0..2047
      int row = c >> 6, p = c & 63;
      int g = p ^ (row & 31);
      gload_lds16(Kg + (size_t)(t0 + row) * 2 * C + g * 8,
                  Kl + (i * 512 + w * 64) * 8);
    }
  };
  auto STAGE_V = [&](int t0) {       // V-tile: 512 c-rows x 32 t
#pragma unroll
    for (int i = 0; i < 4; ++i) {
      int c = i * 512 + tid;
      int row = c >> 2, p = c & 3;
      int g = p ^ ((row & 3) ^ ((row >> 2) & 3));
      gload_lds16(Vg + (size_t)row * S + t0 + g * 8,
                  Vl + (i * 512 + w * 64) * 8);
    }
  };

  f32x4 acc[2][4] = {};              // O: rows 16m+.., cols w*64+16n+..
  float mrow = -1e30f, lrow = 0.f;
  int r = tid >> 4, jc = (tid & 15) * 2;   // softmax assignment

  STAGE_K(0);
  asm volatile("s_waitcnt vmcnt(0)" ::: "memory");
  __builtin_amdgcn_sched_barrier(0);
  __builtin_amdgcn_s_barrier();
  __builtin_amdgcn_sched_barrier(0);

  for (int t0 = 0; t0 < S; t0 += 32) {
    STAGE_V(t0);                     // V buffer free (prev PV done at barrier)
    // ---- S = Q K^T (this wave's 16x16 frag, half-K)
    f32x4 sacc = {0.f, 0.f, 0.f, 0.f};
    int krow = sn * 16 + l15;
#pragma unroll
    for (int kk = 0; kk < 8; ++kk) {
      int gl = wh * 32 + l4 + 4 * kk;
      int p = gl ^ (krow & 31);
      bf16x8 kf = *(const bf16x8*)&Kl[krow * 512 + p * 8];
      sacc = __builtin_amdgcn_mfma_f32_16x16x32_bf16(qreg[kk], kf, sacc, 0, 0, 0);
    }
#pragma unroll
    for (int rr = 0; rr < 4; ++rr)
      Sl[wh][sm * 16 + l4 * 4 + rr][sn * 16 + l15] = sacc[rr];
    __syncthreads();                 // V landed (vmcnt0) + S visible

    // ---- online softmax (16 threads/row, 2 cols each)
    float s0 = (Sl[0][r][jc] + Sl[1][r][jc]) * scl;
    float s1 = (Sl[0][r][jc + 1] + Sl[1][r][jc + 1]) * scl;
    float tmax = fmaxf(s0, s1);
#pragma unroll
    for (int o = 1; o < 16; o <<= 1) tmax = fmaxf(tmax, __shfl_xor(tmax, o));
    float mnew = fmaxf(mrow, tmax);
    float sc = __expf(mrow - mnew);
    float p0 = __expf(s0 - mnew), p1 = __expf(s1 - mnew);
    float es = p0 + p1;
#pragma unroll
    for (int o = 1; o < 16; o <<= 1) es += __shfl_xor(es, o);
    lrow = lrow * sc + es;
    mrow = mnew;
    Pl[r][jc] = f2bf(p0);
    Pl[r][jc + 1] = f2bf(p1);
    if ((tid & 15) == 0) rowf[r] = sc;
    __syncthreads();                 // P + rowf visible, all K-reads done

    // ---- rescale O and PV
    float fsc[2][4];
#pragma unroll
    for (int m = 0; m < 2; ++m)
#pragma unroll
      for (int rr = 0; rr < 4; ++rr)
        fsc[m][rr] = rowf[m * 16 + l4 * 4 + rr];
#pragma unroll
    for (int m = 0; m < 2; ++m)
#pragma unroll
      for (int n = 0; n < 4; ++n)
#pragma unroll
        for (int rr = 0; rr < 4; ++rr)
          acc[m][n][rr] *= fsc[m][rr];

    bf16x8 pf[2], vf[4];
#pragma unroll
    for (int m = 0; m < 2; ++m)
      pf[m] = *(const bf16x8*)&Pl[m * 16 + l15][l4 * 8];
#pragma unroll
    for (int n = 0; n < 4; ++n) {
      int crow = w * 64 + n * 16 + l15;
      int p = l4 ^ ((crow & 3) ^ ((crow >> 2) & 3));
      vf[n] = *(const bf16x8*)&Vl[crow * 32 + p * 8];
    }
    if (t0 + 32 < S) STAGE_K(t0 + 32);  // K buffer free since S-barrier
#pragma unroll
    for (int m = 0; m < 2; ++m)
#pragma unroll
      for (int n = 0; n < 4; ++n)
        acc[m][n] = __builtin_amdgcn_mfma_f32_16x16x32_bf16(
            pf[m], vf[n], acc[m][n], 0, 0, 0);
    asm volatile("s_waitcnt vmcnt(0)" ::: "memory");  // K(t+1) landed
    __builtin_amdgcn_sched_barrier(0);
    __builtin_amdgcn_s_barrier();
    __builtin_amdgcn_sched_barrier(0);
  }

  // ---- epilogue: O /= l, write bf16
  if ((tid & 15) == 0) rowf[r] = 1.f / lrow;
  __syncthreads();
  float fin[2][4];
#pragma unroll
  for (int m = 0; m < 2; ++m)
#pragma unroll
    for (int rr = 0; rr < 4; ++rr)
      fin[m][rr] = rowf[m * 16 + l4 * 4 + rr];
#pragma unroll
  for (int m = 0; m < 2; ++m)
#pragma unroll
    for (int n = 0; n < 4; ++n)
#pragma unroll
      for (int rr = 0; rr < 4; ++rr) {
        int row = q0 + m * 16 + l4 * 4 + rr;
        int col = w * 64 + n * 16 + l15;
        Og[(size_t)row * C + col] = f2bf(acc[m][n][rr] * fin[m][rr]);
      }
}

extern "C" void kernel_launch(void* const* d_in, const int* in_sizes, int n_in,
                              void* d_out, int out_size, void* d_ws, size_t ws_size,
                              hipStream_t stream) {
  const float* x = (const float*)d_in[0];
  const float* gamma = (const float*)d_in[1];
  const float* beta = (const float*)d_in[2];
  const float* wq = (const float*)d_in[3];
  const float* bq = (const float*)d_in[4];
  const float* wk = (const float*)d_in[5];
  const float* bk = (const float*)d_in[6];
  const float* wv = (const float*)d_in[7];
  const float* bv = (const float*)d_in[8];
  const float* wo = (const float*)d_in[9];
  const float* bo = (const float*)d_in[10];

  const int C = 512, S = 1024;
  const int N = in_sizes[0] / (C * S);  // 16
  const long SC = (long)S * C;
  const long S2C = (long)S * 2 * C;
  const int CC = C * C;

  char* ws = (char*)d_ws;
  const size_t MB = 1024 * 1024;
  u16* HT = (u16*)(ws + 0 * MB);      // [N,S,C]   0..16 MB
  u16* QKT = (u16*)(ws + 16 * MB);    // [N,S,2C]  16..48 MB
  u16* Vb = (u16*)(ws + 48 * MB);     // [N,C,S]   48..64 MB
  u16* Wqk = (u16*)(ws + 96 * MB);    // [2C,C]
  u16* Wv = Wqk + 2 * CC;
  u16* Wo = Wv + CC;
  float* bqk = (float*)(Wo + CC);     // [2C]
  u16* H2T = HT;                      // overlay: HT dead after V-GEMM

  cvt_kernel<<<dim3(CC / 1024, 4), 256, 0, stream>>>(wq, wk, wv, wo, Wqk, Wv, Wo, CC);
  biascat_kernel<<<4, 256, 0, stream>>>(bq, bk, bqk, C);
  groupnorm_kernel<<<N * GROUPS, 256, 0, stream>>>(x, gamma, beta, HT, C, S);

  const float scl = 1.0f / sqrtf((float)C);

  // fused Q,K projection: QKT[s][j] = sum_c HT[s][c]*Wqk[j][c] + bqk[j]
  gemm256x128_kernel<<<dim3((S / 256) * (2 * C / 128) * N), 512, 0, stream>>>(
      HT, C, SC, Wqk, C, 0, QKT, 2 * C, S2C, 0, bqk, 2, 1.f, nullptr, C,
      2 * C / 128, S / 256);
  // V[c][s] = sum_k Wv[c][k]*HT[s][k] + bv[c]
  gemm256x128_kernel<<<dim3((C / 256) * (S / 128) * N), 512, 0, stream>>>(
      Wv, C, 0, HT, C, SC, Vb, S, SC, 0, bv, 1, 1.f, nullptr, C,
      S / 128, C / 256);
  // flash attention: H2T[s][c] = softmax(scl * Q K^T) V
  flash_kernel<<<dim3(N * (S / 32)), 512, 0, stream>>>(QKT, Vb, H2T, scl);
  // out[c][s] = x + bo[c] + sum_k Wo[c][k]*H2T[s][k]   (fp32)
  gemm256x128_kernel<<<dim3((C / 256) * (S / 128) * N), 512, 0, stream>>>(
      Wo, C, 0, H2T, C, SC, d_out, S, SC, 1, bo, 1, 1.f, x, C,
      S / 128, C / 256);
}

// Round 14
// 209.058 us; speedup vs baseline: 1.3372x; 1.2263x over previous
//
#include <hip/hip_runtime.h>

#define GROUPS 32
#define EPS 1e-5f

typedef unsigned short u16;
typedef __bf16 bf16x8 __attribute__((ext_vector_type(8)));
typedef float f32x4 __attribute__((ext_vector_type(4)));

__device__ __forceinline__ u16 f2bf(float f) {
  unsigned x = __builtin_bit_cast(unsigned, f);
  x += 0x7FFFu + ((x >> 16) & 1u);
  return (u16)(x >> 16);
}
__device__ __forceinline__ float bf2f(u16 u) {
  unsigned x = ((unsigned)u) << 16;
  return __builtin_bit_cast(float, x);
}

__device__ __forceinline__ void gload_lds16(const void* g, void* l) {
  __builtin_amdgcn_global_load_lds(
      (const __attribute__((address_space(1))) void*)g,
      (__attribute__((address_space(3))) void*)l, 16, 0, 0);
}

// ---------------- weight fp32 -> bf16 (all 4 weights, one dispatch) --------
__global__ __launch_bounds__(256) void cvt_kernel(
    const float* __restrict__ wq, const float* __restrict__ wk,
    const float* __restrict__ wv, const float* __restrict__ wo,
    u16* __restrict__ Wqk, u16* __restrict__ Wv, u16* __restrict__ Wo,
    int n) {
  int i = (blockIdx.x * 256 + threadIdx.x) * 4;
  if (i >= n) return;
  const float* src;
  u16* dst;
  switch (blockIdx.y) {
    case 0: src = wq; dst = Wqk; break;
    case 1: src = wk; dst = Wqk + n; break;
    case 2: src = wv; dst = Wv; break;
    default: src = wo; dst = Wo; break;
  }
  float4 v = *(const float4*)&src[i];
  ushort4 o;
  o.x = f2bf(v.x); o.y = f2bf(v.y); o.z = f2bf(v.z); o.w = f2bf(v.w);
  *(ushort4*)&dst[i] = o;
}

// ---------------- bias concat bq||bk -> fp32[1024] ----------------
__global__ __launch_bounds__(256) void biascat_kernel(
    const float* __restrict__ bq, const float* __restrict__ bk,
    float* __restrict__ bqk, int C) {
  int i = blockIdx.x * 256 + threadIdx.x;
  if (i < C) bqk[i] = bq[i];
  else if (i < 2 * C) bqk[i] = bk[i - C];
}

// ---------------- GroupNorm -> HT [N, S, C] bf16 ----------------
__global__ __launch_bounds__(256) void groupnorm_kernel(
    const float* __restrict__ x, const float* __restrict__ gamma,
    const float* __restrict__ beta, u16* __restrict__ HT, int C, int S) {
  const int cpg = C / GROUPS;  // 16
  __shared__ float xs[16 * 1024];
  __shared__ float rs[4], rss[4];
  int n = blockIdx.x / GROUPS;
  int g = blockIdx.x % GROUPS;
  const float* xb = x + ((size_t)n * C + (size_t)g * cpg) * S;
  int tid = threadIdx.x;
  int cnt = cpg * S;
  float s = 0.f, ss = 0.f;
  for (int i = tid * 4; i < cnt; i += 256 * 4) {
    float4 v = *(const float4*)&xb[i];
    *(float4*)&xs[i] = v;
    s += v.x + v.y + v.z + v.w;
    ss += v.x * v.x + v.y * v.y + v.z * v.z + v.w * v.w;
  }
  for (int o = 32; o > 0; o >>= 1) {
    s += __shfl_xor(s, o);
    ss += __shfl_xor(ss, o);
  }
  int wave = tid >> 6, lane = tid & 63;
  if (lane == 0) { rs[wave] = s; rss[wave] = ss; }
  __syncthreads();
  float S1 = rs[0] + rs[1] + rs[2] + rs[3];
  float S2 = rss[0] + rss[1] + rss[2] + rss[3];
  float mean = S1 / (float)cnt;
  float var = S2 / (float)cnt - mean * mean;
  float rstd = rsqrtf(var + EPS);
  float gm[16], bt[16];
#pragma unroll
  for (int c = 0; c < 16; ++c) {
    float gmv = gamma[g * cpg + c] * rstd;
    gm[c] = gmv;
    bt[c] = beta[g * cpg + c] - mean * gmv;
  }
  for (int i = 0; i < S; i += 256) {
    int sp = i + tid;
    u16 outv[16];
#pragma unroll
    for (int c = 0; c < 16; ++c) {
      float h = xs[c * 1024 + sp] * gm[c] + bt[c];
      outv[c] = f2bf(h);
    }
    u16* dst = HT + ((size_t)n * S + sp) * C + g * cpg;
    *(int4*)dst = *(int4*)&outv[0];
    *(int4*)&dst[8] = *(int4*)&outv[8];
  }
}

// =================== 128x128x128 single-buffer GEMM (4 waves) ==============
// Out[m][n] = scale*sum_k A[m][k]*B[n][k] (+bias/residual)
// Big-step design: BK=128 -> NT = K/128 (4 or 8) steps per block; per step
// { STAGE 64KB; vmcnt(0); barrier; COMPUTE (64 MFMA/wave); barrier }.
// Rationale: dispatch time ~= NT x step-latency (fixed ~6k cy component
// dominated by drain/barrier/convoy, not bytes -- rounds 1-11); fewer,
// bigger steps amortize it. 64KB LDS single-buffered -> 2 blocks/CU.
// Row = 128 bf16 = 16 granules; phys granule p = g ^ (row&15)
// (16 distinct granules per 16-lane fragment read -> 2-way banks = free);
// inverse-swizzled global source, linear gload_lds dest.
// Batch->XCD locality z-map.
__global__ __launch_bounds__(256, 2) void gemm128k_kernel(
    const u16* __restrict__ A, long lda, long strideA,
    const u16* __restrict__ B, long ldb, long strideB,
    void* __restrict__ Out, long ldo, long strideO, int out_fp32,
    const float* __restrict__ bias, int bias_mode,  // 0 none, 1 row, 2 col
    float scale, const float* __restrict__ residual, int K, int nbx, int nby) {
  __shared__ u16 As[16384];  // 128x128 bf16 = 32 KB
  __shared__ u16 Bs[16384];

  int tid = threadIdx.x;
  int wave = tid >> 6, lane = tid & 63;
  int wr = wave >> 1, wc = wave & 1;
  int l15 = lane & 15, l4 = lane >> 4;

  int orig = blockIdx.x;
  int tilesPB = nbx * nby;
  int nz = gridDim.x / tilesPB;
  int z, rem;
  if ((nz & 7) == 0) {        // batch->XCD mapping
    int e = orig & 7, j = orig >> 3;
    z = e + 8 * (j / tilesPB);
    rem = j % tilesPB;
  } else {
    int swz = ((gridDim.x & 7) == 0)
                  ? (orig & 7) * (gridDim.x >> 3) + (orig >> 3) : orig;
    z = swz / tilesPB; rem = swz % tilesPB;
  }
  int bx = rem % nbx, by = rem / nbx;

  const u16* Ab = A + (long)z * strideA + (long)by * 128 * lda;
  const u16* Bb = B + (long)z * strideB + (long)bx * 128 * ldb;

  // stage 128x128 A and B tiles (2048 granules each; 8+8 per thread)
  auto STAGE = [&](int kt) {
#pragma unroll
    for (int i = 0; i < 8; ++i) {
      int c = i * 256 + tid;          // 0..2047
      int row = c >> 4, p = c & 15;
      int g = p ^ (row & 15);         // inverse swizzle on global source
      long koff = (long)kt * 128 + g * 8;
      int lbase = (i * 256 + wave * 64) * 8;  // linear wave-uniform dest
      gload_lds16(Ab + (long)row * lda + koff, As + lbase);
      gload_lds16(Bb + (long)row * ldb + koff, Bs + lbase);
    }
  };

  f32x4 acc[4][4] = {};

  auto COMPUTE = [&]() {
#pragma unroll
    for (int kh = 0; kh < 4; ++kh) {
      bf16x8 af[4], bfr[4];
#pragma unroll
      for (int m = 0; m < 4; ++m) {
        int R = wr * 64 + m * 16 + l15;
        int p = (kh * 4 + l4) ^ (R & 15);
        af[m] = *(const bf16x8*)&As[R * 128 + p * 8];
      }
#pragma unroll
      for (int n = 0; n < 4; ++n) {
        int R = wc * 64 + n * 16 + l15;
        int p = (kh * 4 + l4) ^ (R & 15);
        bfr[n] = *(const bf16x8*)&Bs[R * 128 + p * 8];
      }
#pragma unroll
      for (int m = 0; m < 4; ++m)
#pragma unroll
        for (int n = 0; n < 4; ++n)
          acc[m][n] = __builtin_amdgcn_mfma_f32_16x16x32_bf16(
              af[m], bfr[n], acc[m][n], 0, 0, 0);
    }
  };

  int NT = K >> 7;  // 4 or 8
  for (int t = 0; t < NT; ++t) {
    STAGE(t);
    asm volatile("s_waitcnt vmcnt(0)" ::: "memory");
    __builtin_amdgcn_sched_barrier(0);
    __builtin_amdgcn_s_barrier();      // tile landed for all waves
    __builtin_amdgcn_sched_barrier(0);
    COMPUTE();
    __builtin_amdgcn_s_barrier();      // all reads done before next overwrite
  }

  long orow0 = (long)by * 128 + wr * 64;
  long ocol0 = (long)bx * 128 + wc * 64;
#pragma unroll
  for (int m = 0; m < 4; ++m) {
#pragma unroll
    for (int n = 0; n < 4; ++n) {
#pragma unroll
      for (int r = 0; r < 4; ++r) {
        long row = orow0 + m * 16 + l4 * 4 + r;
        long col = ocol0 + n * 16 + l15;
        float v = acc[m][n][r] * scale;
        if (bias_mode == 1) v += bias[row];
        else if (bias_mode == 2) v += bias[col];
        long off = (long)z * strideO + row * ldo + col;
        if (residual) v += residual[off];
        if (out_fp32) ((float*)Out)[off] = v;
        else ((u16*)Out)[off] = f2bf(v);
      }
    }
  }
}

// ---------------- softmax over rows of P [rows, S] bf16, in place ----------
__global__ __launch_bounds__(256) void softmax_kernel(u16* __restrict__ P, int S) {
  size_t row = blockIdx.x;
  u16* p = P + row * (size_t)S;
  int tid = threadIdx.x;
  ushort4 u = *(const ushort4*)&p[tid * 4];
  float v0 = bf2f(u.x), v1 = bf2f(u.y), v2 = bf2f(u.z), v3 = bf2f(u.w);
  float m = fmaxf(fmaxf(v0, v1), fmaxf(v2, v3));
  for (int o = 32; o > 0; o >>= 1) m = fmaxf(m, __shfl_xor(m, o));
  __shared__ float redm[4], reds[4];
  int wave = tid >> 6, lane = tid & 63;
  if (lane == 0) redm[wave] = m;
  __syncthreads();
  m = fmaxf(fmaxf(redm[0], redm[1]), fmaxf(redm[2], redm[3]));
  float e0 = __expf(v0 - m), e1 = __expf(v1 - m);
  float e2 = __expf(v2 - m), e3 = __expf(v3 - m);
  float s = e0 + e1 + e2 + e3;
  for (int o = 32; o > 0; o >>= 1) s += __shfl_xor(s, o);
  if (lane == 0) reds[wave] = s;
  __syncthreads();
  s = reds[0] + reds[1] + reds[2] + reds[3];
  float inv = 1.f / s;
  ushort4 o4;
  o4.x = f2bf(e0 * inv); o4.y = f2bf(e1 * inv);
  o4.z = f2bf(e2 * inv); o4.w = f2bf(e3 * inv);
  *(ushort4*)&p[tid * 4] = o4;
}

extern "C" void kernel_launch(void* const* d_in, const int* in_sizes, int n_in,
                              void* d_out, int out_size, void* d_ws, size_t ws_size,
                              hipStream_t stream) {
  const float* x = (const float*)d_in[0];
  const float* gamma = (const float*)d_in[1];
  const float* beta = (const float*)d_in[2];
  const float* wq = (const float*)d_in[3];
  const float* bq = (const float*)d_in[4];
  const float* wk = (const float*)d_in[5];
  const float* bk = (const float*)d_in[6];
  const float* wv = (const float*)d_in[7];
  const float* bv = (const float*)d_in[8];
  const float* wo = (const float*)d_in[9];
  const float* bo = (const float*)d_in[10];

  const int C = 512, S = 1024;
  const int N = in_sizes[0] / (C * S);  // 16
  const long SC = (long)S * C;
  const long S2C = (long)S * 2 * C;
  const long SS = (long)S * S;
  const int CC = C * C;

  char* ws = (char*)d_ws;
  const size_t MB = 1024 * 1024;
  u16* HT = (u16*)(ws + 0 * MB);      // [N,S,C]   0..16 MB
  u16* QKT = (u16*)(ws + 16 * MB);    // [N,S,2C]  16..48 MB
  u16* Vb = (u16*)(ws + 48 * MB);     // [N,C,S]   48..64 MB
  u16* P = (u16*)(ws + 64 * MB);      // [N,S,S]   64..96 MB
  u16* Wqk = (u16*)(ws + 96 * MB);    // [2C,C]
  u16* Wv = Wqk + 2 * CC;
  u16* Wo = Wv + CC;
  float* bqk = (float*)(Wo + CC);     // [2C]
  u16* H2T = HT;                      // overlay: HT dead after V-GEMM

  cvt_kernel<<<dim3(CC / 1024, 4), 256, 0, stream>>>(wq, wk, wv, wo, Wqk, Wv, Wo, CC);
  biascat_kernel<<<4, 256, 0, stream>>>(bq, bk, bqk, C);
  groupnorm_kernel<<<N * GROUPS, 256, 0, stream>>>(x, gamma, beta, HT, C, S);

  const float scl = 1.0f / sqrtf((float)C);

  // fused Q,K projection: QKT[s][j] = sum_c HT[s][c]*Wqk[j][c] + bqk[j]
  gemm128k_kernel<<<dim3((S / 128) * (2 * C / 128) * N), 256, 0, stream>>>(
      HT, C, SC, Wqk, C, 0, QKT, 2 * C, S2C, 0, bqk, 2, 1.f, nullptr, C,
      2 * C / 128, S / 128);
  // V[c][s] = sum_k Wv[c][k]*HT[s][k] + bv[c]
  gemm128k_kernel<<<dim3((C / 128) * (S / 128) * N), 256, 0, stream>>>(
      Wv, C, 0, HT, C, SC, Vb, S, SC, 0, bv, 1, 1.f, nullptr, C,
      S / 128, C / 128);
  // P[s][t] = scl * sum_c Q[s][c]*K[t][c]
  gemm128k_kernel<<<dim3((S / 128) * (S / 128) * N), 256, 0, stream>>>(
      QKT, 2 * C, S2C, QKT + C, 2 * C, S2C, P, S, SS, 0, nullptr, 0, scl,
      nullptr, C, S / 128, S / 128);
  softmax_kernel<<<N * S, 256, 0, stream>>>(P, S);
  // H2T[s][c] = sum_t P[s][t]*V[c][t]   (out rows = S, cols = C)
  gemm128k_kernel<<<dim3((C / 128) * (S / 128) * N), 256, 0, stream>>>(
      P, S, SS, Vb, S, SC, H2T, C, SC, 0, nullptr, 0, 1.f, nullptr, S,
      C / 128, S / 128);
  // out[c][s] = x + bo[c] + sum_k Wo[c][k]*H2T[s][k]   (fp32)
  gemm128k_kernel<<<dim3((C / 128) * (S / 128) * N), 256, 0, stream>>>(
      Wo, C, 0, H2T, C, SC, d_out, S, SC, 1, bo, 1, 1.f, x, C,
      S / 128, C / 128);
}

// Round 15
// 175.558 us; speedup vs baseline: 1.5924x; 1.1908x over previous
//
#include <hip/hip_runtime.h>

#define GROUPS 32
#define EPS 1e-5f

typedef unsigned short u16;
typedef __bf16 bf16x8 __attribute__((ext_vector_type(8)));
typedef float f32x4 __attribute__((ext_vector_type(4)));

__device__ __forceinline__ u16 f2bf(float f) {
  unsigned x = __builtin_bit_cast(unsigned, f);
  x += 0x7FFFu + ((x >> 16) & 1u);
  return (u16)(x >> 16);
}
__device__ __forceinline__ float bf2f(u16 u) {
  unsigned x = ((unsigned)u) << 16;
  return __builtin_bit_cast(float, x);
}

__device__ __forceinline__ void gload_lds16(const void* g, void* l) {
  __builtin_amdgcn_global_load_lds(
      (const __attribute__((address_space(1))) void*)g,
      (__attribute__((address_space(3))) void*)l, 16, 0, 0);
}

// -------- weight fp32 -> bf16 (4 weights) + bias concat, one dispatch ------
__global__ __launch_bounds__(256) void cvt_kernel(
    const float* __restrict__ wq, const float* __restrict__ wk,
    const float* __restrict__ wv, const float* __restrict__ wo,
    const float* __restrict__ bq, const float* __restrict__ bk,
    u16* __restrict__ Wqk, u16* __restrict__ Wv, u16* __restrict__ Wo,
    float* __restrict__ bqk, int n, int C) {
  if (blockIdx.y == 4) {   // bias concat bq||bk
    int j = blockIdx.x * 256 + threadIdx.x;
    if (j < C) bqk[j] = bq[j];
    else if (j < 2 * C) bqk[j] = bk[j - C];
    return;
  }
  int i = (blockIdx.x * 256 + threadIdx.x) * 4;
  if (i >= n) return;
  const float* src;
  u16* dst;
  switch (blockIdx.y) {
    case 0: src = wq; dst = Wqk; break;
    case 1: src = wk; dst = Wqk + n; break;
    case 2: src = wv; dst = Wv; break;
    default: src = wo; dst = Wo; break;
  }
  float4 v = *(const float4*)&src[i];
  ushort4 o;
  o.x = f2bf(v.x); o.y = f2bf(v.y); o.z = f2bf(v.z); o.w = f2bf(v.w);
  *(ushort4*)&dst[i] = o;
}

// ---------------- GroupNorm -> HT [N, S, C] bf16 ----------------
__global__ __launch_bounds__(256) void groupnorm_kernel(
    const float* __restrict__ x, const float* __restrict__ gamma,
    const float* __restrict__ beta, u16* __restrict__ HT, int C, int S) {
  const int cpg = C / GROUPS;  // 16
  __shared__ float xs[16 * 1024];
  __shared__ float rs[4], rss[4];
  int n = blockIdx.x / GROUPS;
  int g = blockIdx.x % GROUPS;
  const float* xb = x + ((size_t)n * C + (size_t)g * cpg) * S;
  int tid = threadIdx.x;
  int cnt = cpg * S;
  float s = 0.f, ss = 0.f;
  for (int i = tid * 4; i < cnt; i += 256 * 4) {
    float4 v = *(const float4*)&xb[i];
    *(float4*)&xs[i] = v;
    s += v.x + v.y + v.z + v.w;
    ss += v.x * v.x + v.y * v.y + v.z * v.z + v.w * v.w;
  }
  for (int o = 32; o > 0; o >>= 1) {
    s += __shfl_xor(s, o);
    ss += __shfl_xor(ss, o);
  }
  int wave = tid >> 6, lane = tid & 63;
  if (lane == 0) { rs[wave] = s; rss[wave] = ss; }
  __syncthreads();
  float S1 = rs[0] + rs[1] + rs[2] + rs[3];
  float S2 = rss[0] + rss[1] + rss[2] + rss[3];
  float mean = S1 / (float)cnt;
  float var = S2 / (float)cnt - mean * mean;
  float rstd = rsqrtf(var + EPS);
  float gm[16], bt[16];
#pragma unroll
  for (int c = 0; c < 16; ++c) {
    float gmv = gamma[g * cpg + c] * rstd;
    gm[c] = gmv;
    bt[c] = beta[g * cpg + c] - mean * gmv;
  }
  for (int i = 0; i < S; i += 256) {
    int sp = i + tid;
    u16 outv[16];
#pragma unroll
    for (int c = 0; c < 16; ++c) {
      float h = xs[c * 1024 + sp] * gm[c] + bt[c];
      outv[c] = f2bf(h);
    }
    u16* dst = HT + ((size_t)n * S + sp) * C + g * cpg;
    *(int4*)dst = *(int4*)&outv[0];
    *(int4*)&dst[8] = *(int4*)&outv[8];
  }
}

// =================== 256x128x32 2-phase GEMM body (8 waves) ================
// Round-8 best-measured structure, verbatim, as a device function so
// independent GEMM jobs can share one dispatch.
// Batch->XCD locality z-map (bid&7 -> XCD). LDS line layout (0-conflict):
// two rows interleave into one 64-elem line; granule (l,p) holds global
// (row=2l+(q>>2), kslot=q&3), q=p^(l&7).
__device__ __forceinline__ void gemm_body(
    int bid, int nblk,
    const u16* __restrict__ A, long lda, long strideA,
    const u16* __restrict__ B, long ldb, long strideB,
    void* __restrict__ Out, long ldo, long strideO, int out_fp32,
    const float* __restrict__ bias, int bias_mode,  // 0 none, 1 row, 2 col
    float scale, const float* __restrict__ residual, int K,
    int nbx, int nby, u16* lds) {
  u16* As0 = lds;
  u16* Bs0 = lds + 8192;
  u16* As1 = lds + 12288;
  u16* Bs1 = lds + 20480;

  int tid = threadIdx.x;
  int wave = tid >> 6, lane = tid & 63;
  int wr = wave >> 1, wc = wave & 1;   // 4 x 2 wave grid, 64x64 per wave
  int l15 = lane & 15, l4 = lane >> 4;

  int tilesPB = nbx * nby;
  int nz = nblk / tilesPB;
  int z, rem;
  if ((nz & 7) == 0) {        // batch->XCD mapping
    int e = bid & 7, j = bid >> 3;
    z = e + 8 * (j / tilesPB);
    rem = j % tilesPB;
  } else {
    int swz = ((nblk & 7) == 0) ? (bid & 7) * (nblk >> 3) + (bid >> 3) : bid;
    z = swz / tilesPB; rem = swz % tilesPB;
  }
  int bx = rem % nbx, by = rem / nbx;

  const u16* Ab = A + (long)z * strideA + (long)by * 256 * lda;
  const u16* Bb = B + (long)z * strideB + (long)bx * 128 * ldb;

  auto STAGE = [&](u16* Ad, u16* Bd, int kt) {
#pragma unroll
    for (int i = 0; i < 2; ++i) {       // A granules
      int c = i * 512 + tid;
      int l = c >> 3, p = c & 7;
      int q = p ^ (l & 7);
      int row = 2 * l + (q >> 2);
      long koff = (long)kt * 32 + (q & 3) * 8;
      int lbase = (i * 512 + wave * 64) * 8;
      gload_lds16(Ab + (long)row * lda + koff, Ad + lbase);
    }
    {                                   // B granules
      int c = tid;
      int l = c >> 3, p = c & 7;
      int q = p ^ (l & 7);
      int row = 2 * l + (q >> 2);
      long koff = (long)kt * 32 + (q & 3) * 8;
      int lbase = (wave * 64) * 8;
      gload_lds16(Bb + (long)row * ldb + koff, Bd + lbase);
    }
  };

  f32x4 acc[4][4] = {};

  auto COMPUTE = [&](const u16* Asrc, const u16* Bsrc) {
    bf16x8 af[4], bfr[4];
#pragma unroll
    for (int m = 0; m < 4; ++m) {
      int R = wr * 64 + m * 16 + l15;
      int line = R >> 1;
      int p = ((R & 1) * 4 + l4) ^ (line & 7);
      af[m] = *(const bf16x8*)&Asrc[line * 64 + p * 8];
    }
#pragma unroll
    for (int n = 0; n < 4; ++n) {
      int R = wc * 64 + n * 16 + l15;
      int line = R >> 1;
      int p = ((R & 1) * 4 + l4) ^ (line & 7);
      bfr[n] = *(const bf16x8*)&Bsrc[line * 64 + p * 8];
    }
#pragma unroll
    for (int m = 0; m < 4; ++m)
#pragma unroll
      for (int n = 0; n < 4; ++n)
        acc[m][n] = __builtin_amdgcn_mfma_f32_16x16x32_bf16(
            af[m], bfr[n], acc[m][n], 0, 0, 0);
  };

  int NT = K >> 5;
  u16 *Ar = As0, *Br = Bs0, *Aw = As1, *Bw = Bs1;

  STAGE(Ar, Br, 0);
  asm volatile("s_waitcnt vmcnt(0)" ::: "memory");
  __builtin_amdgcn_sched_barrier(0);
  __builtin_amdgcn_s_barrier();
  __builtin_amdgcn_sched_barrier(0);

  for (int t = 0; t < NT - 1; ++t) {
    STAGE(Aw, Bw, t + 1);       // issue next-tile loads first
    COMPUTE(Ar, Br);            // they fly under ds_read + MFMA
    asm volatile("s_waitcnt vmcnt(0)" ::: "memory");
    __builtin_amdgcn_sched_barrier(0);
    __builtin_amdgcn_s_barrier();
    __builtin_amdgcn_sched_barrier(0);
    u16* tp;
    tp = Ar; Ar = Aw; Aw = tp;
    tp = Br; Br = Bw; Bw = tp;
  }
  COMPUTE(Ar, Br);

  long orow0 = (long)by * 256 + wr * 64;
  long ocol0 = (long)bx * 128 + wc * 64;
#pragma unroll
  for (int m = 0; m < 4; ++m) {
#pragma unroll
    for (int n = 0; n < 4; ++n) {
#pragma unroll
      for (int r = 0; r < 4; ++r) {
        long row = orow0 + m * 16 + l4 * 4 + r;
        long col = ocol0 + n * 16 + l15;
        float v = acc[m][n][r] * scale;
        if (bias_mode == 1) v += bias[row];
        else if (bias_mode == 2) v += bias[col];
        long off = (long)z * strideO + row * ldo + col;
        if (residual) v += residual[off];
        if (out_fp32) ((float*)Out)[off] = v;
        else ((u16*)Out)[off] = f2bf(v);
      }
    }
  }
}

__global__ __launch_bounds__(512, 4) void gemm256x128_kernel(
    const u16* __restrict__ A, long lda, long strideA,
    const u16* __restrict__ B, long ldb, long strideB,
    void* __restrict__ Out, long ldo, long strideO, int out_fp32,
    const float* __restrict__ bias, int bias_mode,
    float scale, const float* __restrict__ residual, int K, int nbx, int nby) {
  __shared__ u16 lds[24576];
  gemm_body(blockIdx.x, gridDim.x, A, lda, strideA, B, ldb, strideB,
            Out, ldo, strideO, out_fp32, bias, bias_mode, scale, residual,
            K, nbx, nby, lds);
}

// -------- merged QK-proj + V-proj: 768 blocks, one dispatch ---------------
// blocks [0, nQK): QKT[s][j] = sum_c HT[s][c]*Wqk[j][c] + bqk[j]
// blocks [nQK, grid): V[c][s] = sum_k Wv[c][k]*HT[s][k] + bv[c]
// Both segment sizes are multiples of 8 -> per-segment batch->XCD map holds.
__global__ __launch_bounds__(512, 4) void projqkv_kernel(
    const u16* __restrict__ HT, const u16* __restrict__ Wqk,
    const u16* __restrict__ Wv, u16* __restrict__ QKT, u16* __restrict__ Vb,
    const float* __restrict__ bqk, const float* __restrict__ bv,
    int nQK, int C, int S) {
  __shared__ u16 lds[24576];
  long SC = (long)S * C, S2C = (long)S * 2 * C;
  if ((int)blockIdx.x < nQK) {
    gemm_body(blockIdx.x, nQK, HT, C, SC, Wqk, C, 0, QKT, 2 * C, S2C, 0,
              bqk, 2, 1.f, nullptr, C, 2 * C / 128, S / 256, lds);
  } else {
    gemm_body(blockIdx.x - nQK, gridDim.x - nQK, Wv, C, 0, HT, C, SC,
              Vb, S, SC, 0, bv, 1, 1.f, nullptr, C, S / 128, C / 256, lds);
  }
}

// ---------------- softmax over rows of P [rows, S] bf16, in place ----------
__global__ __launch_bounds__(256) void softmax_kernel(u16* __restrict__ P, int S) {
  size_t row = blockIdx.x;
  u16* p = P + row * (size_t)S;
  int tid = threadIdx.x;
  ushort4 u = *(const ushort4*)&p[tid * 4];
  float v0 = bf2f(u.x), v1 = bf2f(u.y), v2 = bf2f(u.z), v3 = bf2f(u.w);
  float m = fmaxf(fmaxf(v0, v1), fmaxf(v2, v3));
  for (int o = 32; o > 0; o >>= 1) m = fmaxf(m, __shfl_xor(m, o));
  __shared__ float redm[4], reds[4];
  int wave = tid >> 6, lane = tid & 63;
  if (lane == 0) redm[wave] = m;
  __syncthreads();
  m = fmaxf(fmaxf(redm[0], redm[1]), fmaxf(redm[2], redm[3]));
  float e0 = __expf(v0 - m), e1 = __expf(v1 - m);
  float e2 = __expf(v2 - m), e3 = __expf(v3 - m);
  float s = e0 + e1 + e2 + e3;
  for (int o = 32; o > 0; o >>= 1) s += __shfl_xor(s, o);
  if (lane == 0) reds[wave] = s;
  __syncthreads();
  s = reds[0] + reds[1] + reds[2] + reds[3];
  float inv = 1.f / s;
  ushort4 o4;
  o4.x = f2bf(e0 * inv); o4.y = f2bf(e1 * inv);
  o4.z = f2bf(e2 * inv); o4.w = f2bf(e3 * inv);
  *(ushort4*)&p[tid * 4] = o4;
}

extern "C" void kernel_launch(void* const* d_in, const int* in_sizes, int n_in,
                              void* d_out, int out_size, void* d_ws, size_t ws_size,
                              hipStream_t stream) {
  const float* x = (const float*)d_in[0];
  const float* gamma = (const float*)d_in[1];
  const float* beta = (const float*)d_in[2];
  const float* wq = (const float*)d_in[3];
  const float* bq = (const float*)d_in[4];
  const float* wk = (const float*)d_in[5];
  const float* bk = (const float*)d_in[6];
  const float* wv = (const float*)d_in[7];
  const float* bv = (const float*)d_in[8];
  const float* wo = (const float*)d_in[9];
  const float* bo = (const float*)d_in[10];

  const int C = 512, S = 1024;
  const int N = in_sizes[0] / (C * S);  // 16
  const long SC = (long)S * C;
  const long S2C = (long)S * 2 * C;
  const long SS = (long)S * S;
  const int CC = C * C;

  char* ws = (char*)d_ws;
  const size_t MB = 1024 * 1024;
  u16* HT = (u16*)(ws + 0 * MB);      // [N,S,C]   0..16 MB
  u16* QKT = (u16*)(ws + 16 * MB);    // [N,S,2C]  16..48 MB
  u16* Vb = (u16*)(ws + 48 * MB);     // [N,C,S]   48..64 MB
  u16* P = (u16*)(ws + 64 * MB);      // [N,S,S]   64..96 MB
  u16* Wqk = (u16*)(ws + 96 * MB);    // [2C,C]
  u16* Wv = Wqk + 2 * CC;
  u16* Wo = Wv + CC;
  float* bqk = (float*)(Wo + CC);     // [2C]
  u16* H2T = HT;                      // overlay: HT dead after proj phase

  cvt_kernel<<<dim3(CC / 1024, 5), 256, 0, stream>>>(
      wq, wk, wv, wo, bq, bk, Wqk, Wv, Wo, bqk, CC, C);
  groupnorm_kernel<<<N * GROUPS, 256, 0, stream>>>(x, gamma, beta, HT, C, S);

  const float scl = 1.0f / sqrtf((float)C);
  const int nQK = (S / 256) * (2 * C / 128) * N;   // 512
  const int nV = (C / 256) * (S / 128) * N;        // 256

  // merged QK-proj + V-proj (768 blocks = one full resident generation)
  projqkv_kernel<<<dim3(nQK + nV), 512, 0, stream>>>(
      HT, Wqk, Wv, QKT, Vb, bqk, bv, nQK, C, S);
  // P[s][t] = scl * sum_c Q[s][c]*K[t][c]
  gemm256x128_kernel<<<dim3((S / 256) * (S / 128) * N), 512, 0, stream>>>(
      QKT, 2 * C, S2C, QKT + C, 2 * C, S2C, P, S, SS, 0, nullptr, 0, scl,
      nullptr, C, S / 128, S / 256);
  softmax_kernel<<<N * S, 256, 0, stream>>>(P, S);
  // H2T[s][c] = sum_t P[s][t]*V[c][t]
  gemm256x128_kernel<<<dim3((S / 256) * (C / 128) * N), 512, 0, stream>>>(
      P, S, SS, Vb, S, SC, H2T, C, SC, 0, nullptr, 0, 1.f, nullptr, S,
      C / 128, S / 256);
  // out[c][s] = x + bo[c] + sum_k Wo[c][k]*H2T[s][k]   (fp32)
  gemm256x128_kernel<<<dim3((C / 256) * (S / 128) * N), 512, 0, stream>>>(
      Wo, C, 0, H2T, C, SC, d_out, S, SC, 1, bo, 1, 1.f, x, C,
      S / 128, C / 256);
}

// Round 16
// 162.156 us; speedup vs baseline: 1.7240x; 1.0827x over previous
//
#include <hip/hip_runtime.h>

#define GROUPS 32
#define EPS 1e-5f

typedef unsigned short u16;
typedef __bf16 bf16x8 __attribute__((ext_vector_type(8)));
typedef float f32x4 __attribute__((ext_vector_type(4)));

__device__ __forceinline__ u16 f2bf(float f) {
  unsigned x = __builtin_bit_cast(unsigned, f);
  x += 0x7FFFu + ((x >> 16) & 1u);
  return (u16)(x >> 16);
}
__device__ __forceinline__ float bf2f(u16 u) {
  unsigned x = ((unsigned)u) << 16;
  return __builtin_bit_cast(float, x);
}

__device__ __forceinline__ void gload_lds16(const void* g, void* l) {
  __builtin_amdgcn_global_load_lds(
      (const __attribute__((address_space(1))) void*)g,
      (__attribute__((address_space(3))) void*)l, 16, 0, 0);
}

// ======== prep: groupnorm + weight cvt + bias concat + lsum zero ==========
// blocks [0,512): groupnorm;  [512,1536): weight fp32->bf16 (4 x 256);
// [1536,1540): bias concat;   [1540,1556): zero lsum (N*S floats).
__global__ __launch_bounds__(256) void prep_kernel(
    const float* __restrict__ x, const float* __restrict__ gamma,
    const float* __restrict__ beta, u16* __restrict__ HT,
    const float* __restrict__ wq, const float* __restrict__ wk,
    const float* __restrict__ wv, const float* __restrict__ wo,
    const float* __restrict__ bq, const float* __restrict__ bk,
    u16* __restrict__ Wqk, u16* __restrict__ Wv, u16* __restrict__ Wo,
    float* __restrict__ bqk, float* __restrict__ lsum,
    int C, int S, int CC, int NG) {
  __shared__ float xs[16 * 1024];
  __shared__ float rs[4], rss[4];
  int b = blockIdx.x;
  int tid = threadIdx.x;

  if (b >= NG) {  // ---- cvt / bias / zero branch
    int cb = b - NG;
    if (cb < 1024) {          // weight convert: weight w, block blk
      int w = cb >> 8, blk = cb & 255;
      const float* src;
      u16* dst;
      switch (w) {
        case 0: src = wq; dst = Wqk; break;
        case 1: src = wk; dst = Wqk + CC; break;
        case 2: src = wv; dst = Wv; break;
        default: src = wo; dst = Wo; break;
      }
      int i = (blk * 256 + tid) * 4;
      float4 v = *(const float4*)&src[i];
      ushort4 o;
      o.x = f2bf(v.x); o.y = f2bf(v.y); o.z = f2bf(v.z); o.w = f2bf(v.w);
      *(ushort4*)&dst[i] = o;
    } else if (cb < 1028) {   // bias concat
      int j = (cb - 1024) * 256 + tid;
      if (j < C) bqk[j] = bq[j];
      else if (j < 2 * C) bqk[j] = bk[j - C];
    } else {                  // zero lsum
      int i = (cb - 1028) * 1024 + tid * 4;
      *(float4*)&lsum[i] = make_float4(0.f, 0.f, 0.f, 0.f);
    }
    return;
  }

  // ---- groupnorm branch
  const int cpg = C / GROUPS;  // 16
  int n = b / GROUPS;
  int g = b % GROUPS;
  const float* xb = x + ((size_t)n * C + (size_t)g * cpg) * S;
  int cnt = cpg * S;
  float s = 0.f, ss = 0.f;
  for (int i = tid * 4; i < cnt; i += 256 * 4) {
    float4 v = *(const float4*)&xb[i];
    *(float4*)&xs[i] = v;
    s += v.x + v.y + v.z + v.w;
    ss += v.x * v.x + v.y * v.y + v.z * v.z + v.w * v.w;
  }
  for (int o = 32; o > 0; o >>= 1) {
    s += __shfl_xor(s, o);
    ss += __shfl_xor(ss, o);
  }
  int wave = tid >> 6, lane = tid & 63;
  if (lane == 0) { rs[wave] = s; rss[wave] = ss; }
  __syncthreads();
  float S1 = rs[0] + rs[1] + rs[2] + rs[3];
  float S2 = rss[0] + rss[1] + rss[2] + rss[3];
  float mean = S1 / (float)cnt;
  float var = S2 / (float)cnt - mean * mean;
  float rstd = rsqrtf(var + EPS);
  float gm[16], bt[16];
#pragma unroll
  for (int c = 0; c < 16; ++c) {
    float gmv = gamma[g * cpg + c] * rstd;
    gm[c] = gmv;
    bt[c] = beta[g * cpg + c] - mean * gmv;
  }
  for (int i = 0; i < S; i += 256) {
    int sp = i + tid;
    u16 outv[16];
#pragma unroll
    for (int c = 0; c < 16; ++c) {
      float h = xs[c * 1024 + sp] * gm[c] + bt[c];
      outv[c] = f2bf(h);
    }
    u16* dst = HT + ((size_t)n * S + sp) * C + g * cpg;
    *(int4*)dst = *(int4*)&outv[0];
    *(int4*)&dst[8] = *(int4*)&outv[8];
  }
}

// =================== 256x128x32 2-phase GEMM body (8 waves) ================
// Round-8/15 best-measured structure. Batch->XCD z-map. 0-conflict LDS line
// layout: two rows interleave into one 64-elem line; granule (l,p) holds
// global (row=2l+(q>>2), kslot=q&3), q=p^(l&7).
// epi_mode: 0 = normal (scale/bias/residual/store)
//           1 = expP: write f2bf(exp(acc*scale)); atomic row-sum into epi_ptr
//           2 = colscale: v = acc*scale*(1/epi_ptr[col]) + bias + residual
__device__ __forceinline__ void gemm_body(
    int bid, int nblk,
    const u16* __restrict__ A, long lda, long strideA,
    const u16* __restrict__ B, long ldb, long strideB,
    void* __restrict__ Out, long ldo, long strideO, int out_fp32,
    const float* __restrict__ bias, int bias_mode,  // 0 none, 1 row, 2 col
    float scale, const float* __restrict__ residual, int K,
    int nbx, int nby, u16* lds, int epi_mode, float* epi_ptr) {
  u16* As0 = lds;
  u16* Bs0 = lds + 8192;
  u16* As1 = lds + 12288;
  u16* Bs1 = lds + 20480;

  int tid = threadIdx.x;
  int wave = tid >> 6, lane = tid & 63;
  int wr = wave >> 1, wc = wave & 1;   // 4 x 2 wave grid, 64x64 per wave
  int l15 = lane & 15, l4 = lane >> 4;

  int tilesPB = nbx * nby;
  int nz = nblk / tilesPB;
  int z, rem;
  if ((nz & 7) == 0) {        // batch->XCD mapping
    int e = bid & 7, j = bid >> 3;
    z = e + 8 * (j / tilesPB);
    rem = j % tilesPB;
  } else {
    int swz = ((nblk & 7) == 0) ? (bid & 7) * (nblk >> 3) + (bid >> 3) : bid;
    z = swz / tilesPB; rem = swz % tilesPB;
  }
  int bx = rem % nbx, by = rem / nbx;

  const u16* Ab = A + (long)z * strideA + (long)by * 256 * lda;
  const u16* Bb = B + (long)z * strideB + (long)bx * 128 * ldb;

  auto STAGE = [&](u16* Ad, u16* Bd, int kt) {
#pragma unroll
    for (int i = 0; i < 2; ++i) {       // A granules
      int c = i * 512 + tid;
      int l = c >> 3, p = c & 7;
      int q = p ^ (l & 7);
      int row = 2 * l + (q >> 2);
      long koff = (long)kt * 32 + (q & 3) * 8;
      int lbase = (i * 512 + wave * 64) * 8;
      gload_lds16(Ab + (long)row * lda + koff, Ad + lbase);
    }
    {                                   // B granules
      int c = tid;
      int l = c >> 3, p = c & 7;
      int q = p ^ (l & 7);
      int row = 2 * l + (q >> 2);
      long koff = (long)kt * 32 + (q & 3) * 8;
      int lbase = (wave * 64) * 8;
      gload_lds16(Bb + (long)row * ldb + koff, Bd + lbase);
    }
  };

  f32x4 acc[4][4] = {};

  auto COMPUTE = [&](const u16* Asrc, const u16* Bsrc) {
    bf16x8 af[4], bfr[4];
#pragma unroll
    for (int m = 0; m < 4; ++m) {
      int R = wr * 64 + m * 16 + l15;
      int line = R >> 1;
      int p = ((R & 1) * 4 + l4) ^ (line & 7);
      af[m] = *(const bf16x8*)&Asrc[line * 64 + p * 8];
    }
#pragma unroll
    for (int n = 0; n < 4; ++n) {
      int R = wc * 64 + n * 16 + l15;
      int line = R >> 1;
      int p = ((R & 1) * 4 + l4) ^ (line & 7);
      bfr[n] = *(const bf16x8*)&Bsrc[line * 64 + p * 8];
    }
#pragma unroll
    for (int m = 0; m < 4; ++m)
#pragma unroll
      for (int n = 0; n < 4; ++n)
        acc[m][n] = __builtin_amdgcn_mfma_f32_16x16x32_bf16(
            af[m], bfr[n], acc[m][n], 0, 0, 0);
  };

  int NT = K >> 5;
  u16 *Ar = As0, *Br = Bs0, *Aw = As1, *Bw = Bs1;

  STAGE(Ar, Br, 0);
  asm volatile("s_waitcnt vmcnt(0)" ::: "memory");
  __builtin_amdgcn_sched_barrier(0);
  __builtin_amdgcn_s_barrier();
  __builtin_amdgcn_sched_barrier(0);

  for (int t = 0; t < NT - 1; ++t) {
    STAGE(Aw, Bw, t + 1);       // issue next-tile loads first
    COMPUTE(Ar, Br);            // they fly under ds_read + MFMA
    asm volatile("s_waitcnt vmcnt(0)" ::: "memory");
    __builtin_amdgcn_sched_barrier(0);
    __builtin_amdgcn_s_barrier();
    __builtin_amdgcn_sched_barrier(0);
    u16* tp;
    tp = Ar; Ar = Aw; Aw = tp;
    tp = Br; Br = Bw; Bw = tp;
  }
  COMPUTE(Ar, Br);

  long orow0 = (long)by * 256 + wr * 64;
  long ocol0 = (long)bx * 128 + wc * 64;
  long rows_pb = 256L * nby;
  long cols_pb = 128L * nbx;

  float inv4[4];
  if (epi_mode == 2) {
#pragma unroll
    for (int n = 0; n < 4; ++n)
      inv4[n] = 1.f / epi_ptr[z * cols_pb + ocol0 + n * 16 + l15];
  }
  float rowpart[4][4];
  if (epi_mode == 1) {
#pragma unroll
    for (int m = 0; m < 4; ++m)
#pragma unroll
      for (int r = 0; r < 4; ++r) rowpart[m][r] = 0.f;
  }

#pragma unroll
  for (int m = 0; m < 4; ++m) {
#pragma unroll
    for (int n = 0; n < 4; ++n) {
#pragma unroll
      for (int r = 0; r < 4; ++r) {
        long row = orow0 + m * 16 + l4 * 4 + r;
        long col = ocol0 + n * 16 + l15;
        long off = (long)z * strideO + row * ldo + col;
        float v = acc[m][n][r] * scale;
        if (epi_mode == 1) {
          u16 e = f2bf(__expf(v));
          ((u16*)Out)[off] = e;
          rowpart[m][r] += bf2f(e);
        } else {
          if (epi_mode == 2) v *= inv4[n];
          if (bias_mode == 1) v += bias[row];
          else if (bias_mode == 2) v += bias[col];
          if (residual) v += residual[off];
          if (out_fp32) ((float*)Out)[off] = v;
          else ((u16*)Out)[off] = f2bf(v);
        }
      }
    }
  }

  if (epi_mode == 1) {  // reduce across the 16 cols each lane-group covers
#pragma unroll
    for (int m = 0; m < 4; ++m)
#pragma unroll
      for (int r = 0; r < 4; ++r) {
        float t = rowpart[m][r];
        t += __shfl_xor(t, 1);
        t += __shfl_xor(t, 2);
        t += __shfl_xor(t, 4);
        t += __shfl_xor(t, 8);
        if (l15 == 0) {
          long row = orow0 + m * 16 + l4 * 4 + r;
          atomicAdd(&epi_ptr[z * rows_pb + row], t);
        }
      }
  }
}

__global__ __launch_bounds__(512, 4) void gemm256x128_kernel(
    const u16* __restrict__ A, long lda, long strideA,
    const u16* __restrict__ B, long ldb, long strideB,
    void* __restrict__ Out, long ldo, long strideO, int out_fp32,
    const float* __restrict__ bias, int bias_mode,
    float scale, const float* __restrict__ residual, int K, int nbx, int nby,
    int epi_mode, float* epi_ptr) {
  __shared__ u16 lds[24576];
  gemm_body(blockIdx.x, gridDim.x, A, lda, strideA, B, ldb, strideB,
            Out, ldo, strideO, out_fp32, bias, bias_mode, scale, residual,
            K, nbx, nby, lds, epi_mode, epi_ptr);
}

// -------- merged QK-proj + V-proj: 768 blocks, one dispatch ---------------
__global__ __launch_bounds__(512, 4) void projqkv_kernel(
    const u16* __restrict__ HT, const u16* __restrict__ Wqk,
    const u16* __restrict__ Wv, u16* __restrict__ QKT, u16* __restrict__ Vb,
    const float* __restrict__ bqk, const float* __restrict__ bv,
    int nQK, int C, int S) {
  __shared__ u16 lds[24576];
  long SC = (long)S * C, S2C = (long)S * 2 * C;
  if ((int)blockIdx.x < nQK) {
    gemm_body(blockIdx.x, nQK, HT, C, SC, Wqk, C, 0, QKT, 2 * C, S2C, 0,
              bqk, 2, 1.f, nullptr, C, 2 * C / 128, S / 256, lds, 0, nullptr);
  } else {
    gemm_body(blockIdx.x - nQK, gridDim.x - nQK, Wv, C, 0, HT, C, SC,
              Vb, S, SC, 0, bv, 1, 1.f, nullptr, C, S / 128, C / 256, lds,
              0, nullptr);
  }
}

extern "C" void kernel_launch(void* const* d_in, const int* in_sizes, int n_in,
                              void* d_out, int out_size, void* d_ws, size_t ws_size,
                              hipStream_t stream) {
  const float* x = (const float*)d_in[0];
  const float* gamma = (const float*)d_in[1];
  const float* beta = (const float*)d_in[2];
  const float* wq = (const float*)d_in[3];
  const float* bq = (const float*)d_in[4];
  const float* wk = (const float*)d_in[5];
  const float* bk = (const float*)d_in[6];
  const float* wv = (const float*)d_in[7];
  const float* bv = (const float*)d_in[8];
  const float* wo = (const float*)d_in[9];
  const float* bo = (const float*)d_in[10];

  const int C = 512, S = 1024;
  const int N = in_sizes[0] / (C * S);  // 16
  const long SC = (long)S * C;
  const long S2C = (long)S * 2 * C;
  const long SS = (long)S * S;
  const int CC = C * C;

  char* ws = (char*)d_ws;
  const size_t MB = 1024 * 1024;
  u16* HT = (u16*)(ws + 0 * MB);      // [N,S,C]   0..16 MB
  u16* QKT = (u16*)(ws + 16 * MB);    // [N,S,2C]  16..48 MB
  u16* Vb = (u16*)(ws + 48 * MB);     // [N,C,S]   48..64 MB
  u16* P = (u16*)(ws + 64 * MB);      // [N,S,S]   64..96 MB
  u16* Wqk = (u16*)(ws + 96 * MB);    // [2C,C]
  u16* Wv = Wqk + 2 * CC;
  u16* Wo = Wv + CC;
  float* bqk = (float*)(Wo + CC);     // [2C]
  float* lsum = bqk + 2 * C;          // [N*S] fp32 row sums of expP
  u16* H2T = HT;                      // overlay: HT dead after proj phase

  const int NG = N * GROUPS;          // 512

  // prep: groupnorm + weight cvt + bias concat + zero lsum, one dispatch
  prep_kernel<<<dim3(NG + 1024 + 4 + 16), 256, 0, stream>>>(
      x, gamma, beta, HT, wq, wk, wv, wo, bq, bk, Wqk, Wv, Wo, bqk, lsum,
      C, S, CC, NG);

  const float scl = 1.0f / sqrtf((float)C);
  const int nQK = (S / 256) * (2 * C / 128) * N;   // 512
  const int nV = (C / 256) * (S / 128) * N;        // 256

  // merged QK-proj + V-proj
  projqkv_kernel<<<dim3(nQK + nV), 512, 0, stream>>>(
      HT, Wqk, Wv, QKT, Vb, bqk, bv, nQK, C, S);
  // expP[s][t] = exp(scl * sum_c Q[s][c]*K[t][c]); lsum[s] += row sums
  gemm256x128_kernel<<<dim3((S / 256) * (S / 128) * N), 512, 0, stream>>>(
      QKT, 2 * C, S2C, QKT + C, 2 * C, S2C, P, S, SS, 0, nullptr, 0, scl,
      nullptr, C, S / 128, S / 256, 1, lsum);
  // H2Traw[s][c] = sum_t expP[s][t]*V[c][t]
  gemm256x128_kernel<<<dim3((S / 256) * (C / 128) * N), 512, 0, stream>>>(
      P, S, SS, Vb, S, SC, H2T, C, SC, 0, nullptr, 0, 1.f, nullptr, S,
      C / 128, S / 256, 0, nullptr);
  // out[c][s] = x + bo[c] + (sum_k Wo[c][k]*H2Traw[s][k]) / lsum[s]  (fp32)
  gemm256x128_kernel<<<dim3((C / 256) * (S / 128) * N), 512, 0, stream>>>(
      Wo, C, 0, H2T, C, SC, d_out, S, SC, 1, bo, 1, 1.f, x, C,
      S / 128, C / 256, 2, lsum);
}